// Round 4
// baseline (396.374 us; speedup 1.0000x reference)
//
#include <hip/hip_runtime.h>
#include <hip/hip_bf16.h>
#include <math.h>

#define IN_DIM 128
#define OUT_DIM 128
#define HEADS 4
#define HEAD_DIM 32
#define NREL 3
#define NEG_SLOPE 0.2f

typedef __attribute__((ext_vector_type(8))) short short8;
typedef __attribute__((ext_vector_type(4))) float f32x4;
typedef unsigned short u16;

static __device__ __forceinline__ float leaky(float x){ return fmaxf(x, NEG_SLOPE*x); }
static __device__ __forceinline__ unsigned bf16rn(float x){
  unsigned b = __float_as_uint(x);
  b += 0x7FFF + ((b>>16)&1u);
  return b>>16;
}

// --- softmax over the 3 relation weights ---
__global__ void k_prep(const float* __restrict__ rw, float* __restrict__ smw){
  if (threadIdx.x==0){
    float m = fmaxf(rw[0], fmaxf(rw[1], rw[2]));
    float e0=__expf(rw[0]-m), e1=__expf(rw[1]-m), e2=__expf(rw[2]-m);
    float inv = 1.f/(e0+e1+e2);
    smw[0]=e0*inv; smw[1]=e1*inv; smw[2]=e2*inv;
  }
}

// --- build WTall[r][144][128] bf16: cols 0..127 = W^T, 128..135 = (W@att)^T, 136..143 = 0 ---
__global__ void k_wprep(const float* __restrict__ W, const float* __restrict__ att_s,
                        const float* __restrict__ att_d, u16* __restrict__ WTall){
  const int r = blockIdx.x;
  const int t = threadIdx.x;
  const float* Wr = W + (size_t)r*IN_DIM*OUT_DIM;
  u16* WT = WTall + (size_t)r*144*128;
  for (int i=t; i<128*128; i+=256){
    int k = i>>7, col = i&127;
    WT[col*128 + k] = (u16)bf16rn(Wr[i]);
  }
  if (t < 128){
    int k = t;
    for (int h=0; h<4; h++){
      float ss=0.f, sd=0.f;
      for (int c=0; c<32; c++){
        float w = Wr[k*128 + h*32 + c];
        ss = fmaf(w, att_s[(r*4+h)*32+c], ss);
        sd = fmaf(w, att_d[(r*4+h)*32+c], sd);
      }
      WT[(128+h)*128 + k] = (u16)bf16rn(ss);
      WT[(132+h)*128 + k] = (u16)bf16rn(sd);
    }
  }
  for (int i=t; i<8*128; i+=256) WT[136*128 + i] = 0;
}

// --- MFMA GEMM: h = x@W (bf16 in, fp32 acc) + fused a_s/a_d via extra B columns ---
__global__ __launch_bounds__(256) void k_gemm(
    const float* __restrict__ x, const u16* __restrict__ WTall,
    unsigned* __restrict__ hq, float* __restrict__ as_, float* __restrict__ ad_, int N){
  const int r = blockIdx.y;
  const int w = threadIdx.x >> 6;
  const int l = threadIdx.x & 63;
  const int row0 = blockIdx.x*128 + w*32;
  const int lg = l >> 4;
  const int lc = l & 15;

  const u16* WT = WTall + (size_t)r*144*128;

  f32x4 acc[2][9];
  #pragma unroll
  for (int rf=0; rf<2; rf++)
    #pragma unroll
    for (int cf=0; cf<9; cf++) acc[rf][cf] = (f32x4){0.f,0.f,0.f,0.f};

  for (int ks=0; ks<4; ks++){
    const int k0 = ks*32 + lg*8;
    short8 a[2];
    #pragma unroll
    for (int rf=0; rf<2; rf++){
      int row = row0 + rf*16 + lc;
      float4 v0, v1;
      if (row < N){
        const float4* xp = (const float4*)(x + (size_t)row*IN_DIM + k0);
        v0 = xp[0]; v1 = xp[1];
      } else { v0 = float4{0.f,0.f,0.f,0.f}; v1 = v0; }
      union { short8 s; unsigned u[4]; } pa;
      pa.u[0] = bf16rn(v0.x) | (bf16rn(v0.y)<<16);
      pa.u[1] = bf16rn(v0.z) | (bf16rn(v0.w)<<16);
      pa.u[2] = bf16rn(v1.x) | (bf16rn(v1.y)<<16);
      pa.u[3] = bf16rn(v1.z) | (bf16rn(v1.w)<<16);
      a[rf] = pa.s;
    }
    #pragma unroll
    for (int cf=0; cf<9; cf++){
      union { short8 s; uint4 u; } pb;
      pb.u = *(const uint4*)(WT + (size_t)(cf*16 + lc)*128 + k0);
      #pragma unroll
      for (int rf=0; rf<2; rf++)
        acc[rf][cf] = __builtin_amdgcn_mfma_f32_16x16x32_bf16(a[rf], pb.s, acc[rf][cf], 0, 0, 0);
    }
  }

  #pragma unroll
  for (int rf=0; rf<2; rf++){
    #pragma unroll
    for (int j=0; j<4; j++){
      int row = row0 + rf*16 + lg*4 + j;
      bool ok = (row < N);
      size_t nidx = (size_t)r*N + row;
      #pragma unroll
      for (int cf=0; cf<8; cf++){
        float v = acc[rf][cf][j];
        float pv = __shfl_xor(v, 1);
        if (ok && !(l&1))
          hq[nidx*64 + cf*8 + (lc>>1)] = bf16rn(v) | (bf16rn(pv)<<16);
      }
      float av = acc[rf][8][j];
      if (ok && lc < 4)       as_[nidx*4 + lc]     = av;
      else if (ok && lc < 8)  ad_[nidx*4 + (lc-4)] = av;
    }
  }
}

// --- CSR build: count per (rel,dst); cache key per edge ---
__global__ void k_count(const int* __restrict__ et, const int* __restrict__ ei,
                        int* __restrict__ counts, int* __restrict__ keys, int E, int N){
  int e = blockIdx.x*256 + threadIdx.x;
  if (e >= E) return;
  int ty = et[e];
  int d  = ei[E + e];
  int key = ty*N + d;
  keys[e] = key;
  atomicAdd(&counts[key], 1);
}

// --- 3-kernel exclusive scan over M = 3N elements ---
__global__ void k_scan1(const int* __restrict__ counts, int* __restrict__ offs,
                        int* __restrict__ aux, int M){
  __shared__ int s[256];
  int idx = blockIdx.x*256 + threadIdx.x;
  int v = (idx < M) ? counts[idx] : 0;
  s[threadIdx.x] = v; __syncthreads();
  int x = v;
  for (int off=1; off<256; off<<=1){
    int y = (threadIdx.x >= off) ? s[threadIdx.x-off] : 0;
    __syncthreads();
    x += y; s[threadIdx.x] = x;
    __syncthreads();
  }
  if (idx < M) offs[idx] = x - v;
  if (threadIdx.x == 255) aux[blockIdx.x] = x;
}
__global__ void k_scan2(int* __restrict__ aux, int* __restrict__ offs, int M, int NB){
  __shared__ int s[1024];
  int t = threadIdx.x;
  int v = (t < NB) ? aux[t] : 0;
  s[t] = v; __syncthreads();
  int x = v;
  for (int off=1; off<1024; off<<=1){
    int y = (t >= off) ? s[t-off] : 0;
    __syncthreads();
    x += y; s[t] = x;
    __syncthreads();
  }
  if (t < NB) aux[t] = x - v;
  if (t == NB-1) offs[M] = x;
}
__global__ void k_scan3(int* __restrict__ offs, int* __restrict__ cursor,
                        const int* __restrict__ aux, int M){
  int idx = blockIdx.x*256 + threadIdx.x;
  if (idx < M){
    int v = offs[idx] + aux[idx>>8];
    offs[idx] = v;
    cursor[idx] = v;
  }
}

// --- scatter: only src index, CSR order ---
__global__ void k_scatter(const int* __restrict__ keys, const int* __restrict__ ei,
                          int* __restrict__ cursor, int* __restrict__ ssrc, int E){
  int e = blockIdx.x*256 + threadIdx.x;
  if (e >= E) return;
  int key = keys[e];
  int s   = ei[e];
  int pos = atomicAdd(&cursor[key], 1);
  ssrc[pos] = s;
}

// --- per-dst: single fused pass (no max shift): num += e*h, den += e, scale at end ---
__global__ __launch_bounds__(256) void k_segment(
    const int* __restrict__ offs, const int* __restrict__ ssrc,
    const unsigned* __restrict__ hq,
    const float* __restrict__ as_, const float* __restrict__ ad_,
    const float* __restrict__ bias, const float* __restrict__ smw,
    float* __restrict__ out, int N){
  const int wave = threadIdx.x >> 6;
  const int lane = threadIdx.x & 63;
  const int dst  = blockIdx.x*4 + wave;
  if (dst >= N) return;
  const int g  = lane >> 3;   // edge group 0..7
  const int l8 = lane & 7;    // channel slot in group
  const int h0 = (l8 >> 2) & 1;

  float sw[NREL];
  sw[0] = smw[0]; sw[1] = smw[1]; sw[2] = smw[2];

  float accT0[8], accT1[8];
  #pragma unroll
  for (int q=0; q<8; q++){ accT0[q]=0.f; accT1[q]=0.f; }

  #pragma unroll
  for (int r=0; r<NREL; r++){
    const size_t seg = (size_t)r*N + dst;
    int beg = __builtin_amdgcn_readfirstlane(offs[seg]);
    int end = __builtin_amdgcn_readfirstlane(offs[seg+1]);

    float4 a = ((const float4*)as_)[seg];
    float4 b = ((const float4*)ad_)[seg];
    // self-loop score comps for this lane's two heads
    float sv0 = leaky((h0 ? a.y : a.x) + (h0 ? b.y : b.x));
    float sv1 = leaky((h0 ? a.w : a.z) + (h0 ? b.w : b.z));
    float es0 = __expf(sv0), es1 = __expf(sv1);
    float adv0 = h0 ? b.y : b.x;
    float adv1 = h0 ? b.w : b.z;

    float den0 = 0.f, den1 = 0.f;
    float acc0[8], acc1[8];
    #pragma unroll
    for (int q=0; q<8; q++){ acc0[q]=0.f; acc1[q]=0.f; }

    const unsigned* hb = hq + (size_t)r*N*64;
    const float4* atab = (const float4*)as_ + (size_t)r*N;
    for (int i0=beg; i0<end; i0+=8){
      int i = i0 + g;
      if (i < end){
        int s = ssrc[i];
        float4 a4 = atab[s];
        float s0 = (h0 ? a4.y : a4.x) + adv0;
        float s1 = (h0 ? a4.w : a4.z) + adv1;
        float e0 = __expf(leaky(s0));
        float e1 = __expf(leaky(s1));
        den0 += e0; den1 += e1;
        const uint4* hp = (const uint4*)(hb + (size_t)s*64 + l8*4);
        uint4 u0 = hp[0];
        uint4 u1 = hp[8];
        const unsigned* p0 = (const unsigned*)&u0;
        const unsigned* p1 = (const unsigned*)&u1;
        #pragma unroll
        for (int q=0; q<4; q++){
          acc0[2*q]   = fmaf(e0, __uint_as_float(p0[q]<<16),           acc0[2*q]);
          acc0[2*q+1] = fmaf(e0, __uint_as_float(p0[q] & 0xFFFF0000u), acc0[2*q+1]);
          acc1[2*q]   = fmaf(e1, __uint_as_float(p1[q]<<16),           acc1[2*q]);
          acc1[2*q+1] = fmaf(e1, __uint_as_float(p1[q] & 0xFFFF0000u), acc1[2*q+1]);
        }
      }
    }
    // self-loop message (group 0 only; den handled uniformly below)
    if (g == 0){
      const uint4* hp = (const uint4*)(hb + (size_t)dst*64 + l8*4);
      uint4 u0 = hp[0];
      uint4 u1 = hp[8];
      const unsigned* p0 = (const unsigned*)&u0;
      const unsigned* p1 = (const unsigned*)&u1;
      #pragma unroll
      for (int q=0; q<4; q++){
        acc0[2*q]   = fmaf(es0, __uint_as_float(p0[q]<<16),           acc0[2*q]);
        acc0[2*q+1] = fmaf(es0, __uint_as_float(p0[q] & 0xFFFF0000u), acc0[2*q+1]);
        acc1[2*q]   = fmaf(es1, __uint_as_float(p1[q]<<16),           acc1[2*q]);
        acc1[2*q+1] = fmaf(es1, __uint_as_float(p1[q] & 0xFFFF0000u), acc1[2*q+1]);
      }
    }
    // reduce den across the 8 groups (bits 3..5); lanes within group hold identical sums
    #pragma unroll
    for (int o=8; o<=32; o<<=1){
      den0 += __shfl_xor(den0, o);
      den1 += __shfl_xor(den1, o);
    }
    den0 += es0; den1 += es1;
    float iv0 = sw[r] / den0;
    float iv1 = sw[r] / den1;
    #pragma unroll
    for (int q=0; q<8; q++){
      accT0[q] = fmaf(iv0, acc0[q], accT0[q]);
      accT1[q] = fmaf(iv1, acc1[q], accT1[q]);
    }
  }

  // cross-group reduction (xor 8,16,32)
  #pragma unroll
  for (int o=8; o<=32; o<<=1){
    #pragma unroll
    for (int q=0; q<8; q++){
      accT0[q] += __shfl_xor(accT0[q], o);
      accT1[q] += __shfl_xor(accT1[q], o);
    }
  }

  if (g == 0){
    float b0[8], b1[8];
    #pragma unroll
    for (int q=0; q<8; q++){ b0[q]=0.f; b1[q]=0.f; }
    #pragma unroll
    for (int r=0; r<NREL; r++){
      const float* bp = bias + (size_t)r*OUT_DIM;
      float4 x0 = *(const float4*)(bp + 8*l8);
      float4 x1 = *(const float4*)(bp + 8*l8 + 4);
      float4 y0 = *(const float4*)(bp + 64 + 8*l8);
      float4 y1 = *(const float4*)(bp + 64 + 8*l8 + 4);
      float w = sw[r];
      b0[0]=fmaf(w,x0.x,b0[0]); b0[1]=fmaf(w,x0.y,b0[1]); b0[2]=fmaf(w,x0.z,b0[2]); b0[3]=fmaf(w,x0.w,b0[3]);
      b0[4]=fmaf(w,x1.x,b0[4]); b0[5]=fmaf(w,x1.y,b0[5]); b0[6]=fmaf(w,x1.z,b0[6]); b0[7]=fmaf(w,x1.w,b0[7]);
      b1[0]=fmaf(w,y0.x,b1[0]); b1[1]=fmaf(w,y0.y,b1[1]); b1[2]=fmaf(w,y0.z,b1[2]); b1[3]=fmaf(w,y0.w,b1[3]);
      b1[4]=fmaf(w,y1.x,b1[4]); b1[5]=fmaf(w,y1.y,b1[5]); b1[6]=fmaf(w,y1.z,b1[6]); b1[7]=fmaf(w,y1.w,b1[7]);
    }
    float* orow = out + (size_t)dst*128;
    float4 o0 = {accT0[0]+b0[0], accT0[1]+b0[1], accT0[2]+b0[2], accT0[3]+b0[3]};
    float4 o1 = {accT0[4]+b0[4], accT0[5]+b0[5], accT0[6]+b0[6], accT0[7]+b0[7]};
    float4 o2 = {accT1[0]+b1[0], accT1[1]+b1[1], accT1[2]+b1[2], accT1[3]+b1[3]};
    float4 o3 = {accT1[4]+b1[4], accT1[5]+b1[5], accT1[6]+b1[6], accT1[7]+b1[7]};
    *(float4*)(orow + 8*l8)          = o0;
    *(float4*)(orow + 8*l8 + 4)      = o1;
    *(float4*)(orow + 64 + 8*l8)     = o2;
    *(float4*)(orow + 64 + 8*l8 + 4) = o3;
  }
}

extern "C" void kernel_launch(void* const* d_in, const int* in_sizes, int n_in,
                              void* d_out, int out_size, void* d_ws, size_t ws_size,
                              hipStream_t stream) {
  const float* x     = (const float*)d_in[0];
  const float* W     = (const float*)d_in[1];
  const float* att_s = (const float*)d_in[2];
  const float* att_d = (const float*)d_in[3];
  const float* bias  = (const float*)d_in[4];
  const float* rw    = (const float*)d_in[5];
  const int*   ei    = (const int*)d_in[6];
  const int*   et    = (const int*)d_in[7];
  float* out = (float*)d_out;

  const int N = in_sizes[0] / IN_DIM;
  const int E = in_sizes[7];
  const int M = NREL * N;

  char* ws = (char*)d_ws;
  size_t off = 0;
  auto alloc = [&](size_t bytes) -> void* {
    void* p = ws + off; off += (bytes + 255) & ~(size_t)255; return p;
  };
  unsigned* hq     = (unsigned*)alloc((size_t)M * 64 * 4);
  float*    as_    = (float*)   alloc((size_t)M * 4 * 4);
  float*    ad_    = (float*)   alloc((size_t)M * 4 * 4);
  int*      counts = (int*)     alloc((size_t)M * 4);
  int*      offs   = (int*)     alloc(((size_t)M + 1) * 4);
  int*      cursor = (int*)     alloc((size_t)M * 4);
  int*      aux    = (int*)     alloc(4096);
  int*      ssrc   = (int*)     alloc((size_t)E * 4);
  int*      keys   = (int*)     alloc((size_t)E * 4);
  float*    smw    = (float*)   alloc(256);
  u16*      WTall  = (u16*)     alloc((size_t)NREL * 144 * 128 * 2);

  hipMemsetAsync(counts, 0, (size_t)M * 4, stream);
  k_prep<<<1, 64, 0, stream>>>(rw, smw);
  k_wprep<<<NREL, 256, 0, stream>>>(W, att_s, att_d, WTall);
  dim3 g1((N + 127) / 128, NREL);
  k_gemm<<<g1, 256, 0, stream>>>(x, WTall, hq, as_, ad_, N);
  k_count<<<(E + 255) / 256, 256, 0, stream>>>(et, ei, counts, keys, E, N);
  const int NB = (M + 255) / 256;
  k_scan1<<<NB, 256, 0, stream>>>(counts, offs, aux, M);
  k_scan2<<<1, 1024, 0, stream>>>(aux, offs, M, NB);
  k_scan3<<<NB, 256, 0, stream>>>(offs, cursor, aux, M);
  k_scatter<<<(E + 255) / 256, 256, 0, stream>>>(keys, ei, cursor, ssrc, E);
  k_segment<<<(N + 3) / 4, 256, 0, stream>>>(offs, ssrc, hq, as_, ad_, bias, smw, out, N);
}

// Round 5
// 301.086 us; speedup vs baseline: 1.3165x; 1.3165x over previous
//
#include <hip/hip_runtime.h>
#include <hip/hip_bf16.h>
#include <math.h>

#define IN_DIM 128
#define OUT_DIM 128
#define HEADS 4
#define HEAD_DIM 32
#define NREL 3
#define NEG_SLOPE 0.2f

#define CHUNK 16384         // edges per partition chunk
#define BUCK_SHIFT 8
#define DPB 256             // dsts per bucket
#define KPB 768             // keys per bucket (DPB * NREL)
// assumes N <= 65536 (bucket count <= 256, src fits in 16 bits)

typedef __attribute__((ext_vector_type(8))) short short8;
typedef __attribute__((ext_vector_type(4))) float f32x4;
typedef unsigned short u16;

static __device__ __forceinline__ float leaky(float x){ return fmaxf(x, NEG_SLOPE*x); }
static __device__ __forceinline__ unsigned bf16rn(float x){
  unsigned b = __float_as_uint(x);
  b += 0x7FFF + ((b>>16)&1u);
  return b>>16;
}

// --- softmax over the 3 relation weights ---
__global__ void k_prep(const float* __restrict__ rw, float* __restrict__ smw){
  if (threadIdx.x==0){
    float m = fmaxf(rw[0], fmaxf(rw[1], rw[2]));
    float e0=__expf(rw[0]-m), e1=__expf(rw[1]-m), e2=__expf(rw[2]-m);
    float inv = 1.f/(e0+e1+e2);
    smw[0]=e0*inv; smw[1]=e1*inv; smw[2]=e2*inv;
  }
}

// --- build WTall[r][144][128] bf16: cols 0..127 = W^T, 128..135 = (W@att)^T, 136..143 = 0 ---
__global__ void k_wprep(const float* __restrict__ W, const float* __restrict__ att_s,
                        const float* __restrict__ att_d, u16* __restrict__ WTall){
  const int r = blockIdx.x;
  const int t = threadIdx.x;
  const float* Wr = W + (size_t)r*IN_DIM*OUT_DIM;
  u16* WT = WTall + (size_t)r*144*128;
  for (int i=t; i<128*128; i+=256){
    int k = i>>7, col = i&127;
    WT[col*128 + k] = (u16)bf16rn(Wr[i]);
  }
  if (t < 128){
    int k = t;
    for (int h=0; h<4; h++){
      float ss=0.f, sd=0.f;
      for (int c=0; c<32; c++){
        float w = Wr[k*128 + h*32 + c];
        ss = fmaf(w, att_s[(r*4+h)*32+c], ss);
        sd = fmaf(w, att_d[(r*4+h)*32+c], sd);
      }
      WT[(128+h)*128 + k] = (u16)bf16rn(ss);
      WT[(132+h)*128 + k] = (u16)bf16rn(sd);
    }
  }
  for (int i=t; i<8*128; i+=256) WT[136*128 + i] = 0;
}

// --- MFMA GEMM: h = x@W (bf16 in, fp32 acc) + fused a_s/a_d via extra B columns ---
__global__ __launch_bounds__(256) void k_gemm(
    const float* __restrict__ x, const u16* __restrict__ WTall,
    unsigned* __restrict__ hq, float* __restrict__ as_, float* __restrict__ ad_, int N){
  const int r = blockIdx.y;
  const int w = threadIdx.x >> 6;
  const int l = threadIdx.x & 63;
  const int row0 = blockIdx.x*128 + w*32;
  const int lg = l >> 4;
  const int lc = l & 15;

  const u16* WT = WTall + (size_t)r*144*128;

  f32x4 acc[2][9];
  #pragma unroll
  for (int rf=0; rf<2; rf++)
    #pragma unroll
    for (int cf=0; cf<9; cf++) acc[rf][cf] = (f32x4){0.f,0.f,0.f,0.f};

  for (int ks=0; ks<4; ks++){
    const int k0 = ks*32 + lg*8;
    short8 a[2];
    #pragma unroll
    for (int rf=0; rf<2; rf++){
      int row = row0 + rf*16 + lc;
      float4 v0, v1;
      if (row < N){
        const float4* xp = (const float4*)(x + (size_t)row*IN_DIM + k0);
        v0 = xp[0]; v1 = xp[1];
      } else { v0 = float4{0.f,0.f,0.f,0.f}; v1 = v0; }
      union { short8 s; unsigned u[4]; } pa;
      pa.u[0] = bf16rn(v0.x) | (bf16rn(v0.y)<<16);
      pa.u[1] = bf16rn(v0.z) | (bf16rn(v0.w)<<16);
      pa.u[2] = bf16rn(v1.x) | (bf16rn(v1.y)<<16);
      pa.u[3] = bf16rn(v1.z) | (bf16rn(v1.w)<<16);
      a[rf] = pa.s;
    }
    #pragma unroll
    for (int cf=0; cf<9; cf++){
      union { short8 s; uint4 u; } pb;
      pb.u = *(const uint4*)(WT + (size_t)(cf*16 + lc)*128 + k0);
      #pragma unroll
      for (int rf=0; rf<2; rf++)
        acc[rf][cf] = __builtin_amdgcn_mfma_f32_16x16x32_bf16(a[rf], pb.s, acc[rf][cf], 0, 0, 0);
    }
  }

  #pragma unroll
  for (int rf=0; rf<2; rf++){
    #pragma unroll
    for (int j=0; j<4; j++){
      int row = row0 + rf*16 + lg*4 + j;
      bool ok = (row < N);
      size_t nidx = (size_t)r*N + row;
      #pragma unroll
      for (int cf=0; cf<8; cf++){
        float v = acc[rf][cf][j];
        float pv = __shfl_xor(v, 1);
        if (ok && !(l&1))
          hq[nidx*64 + cf*8 + (lc>>1)] = bf16rn(v) | (bf16rn(pv)<<16);
      }
      float av = acc[rf][8][j];
      if (ok && lc < 4)       as_[nidx*4 + lc]     = av;
      else if (ok && lc < 8)  ad_[nidx*4 + (lc-4)] = av;
    }
  }
}

// --- pass 1: per-chunk histogram over dst buckets ---
__global__ __launch_bounds__(256) void k_hist(const int* __restrict__ ei,
                       int* __restrict__ histG, int E, int NCHUNK, int NBUCK){
  __shared__ int h[256];
  const int c = blockIdx.x, t = threadIdx.x;
  h[t] = 0; __syncthreads();
  const int* dstp = ei + E;
  const int base = c*CHUNK;
  #pragma unroll 4
  for (int it=0; it<CHUNK/256; ++it){
    int e = base + it*256 + t;
    if (e < E) atomicAdd(&h[dstp[e]>>BUCK_SHIFT], 1);
  }
  __syncthreads();
  if (t < NBUCK) histG[t*NCHUNK + c] = h[t];
}

// --- pass 2: exclusive scan of histG (bucket-major), in place; one block ---
__global__ __launch_bounds__(256) void k_scanH(int* __restrict__ histG, int T){
  __shared__ int ps[256];
  const int t = threadIdx.x;
  const int L = (T + 255)/256;
  const int base = t*L;
  int sum = 0;
  for (int i=0;i<L;i++){ int idx=base+i; if(idx<T) sum += histG[idx]; }
  ps[t] = sum; __syncthreads();
  int x = sum;
  for (int off=1; off<256; off<<=1){
    int y = (t>=off)?ps[t-off]:0; __syncthreads();
    x += y; ps[t] = x; __syncthreads();
  }
  int run = x - sum;
  for (int i=0;i<L;i++){
    int idx=base+i;
    if (idx<T){ int v = histG[idx]; histG[idx] = run; run += v; }
  }
}

// --- pass 3: partition edges into buckets; packed payload (src<<10 | rel<<8 | dstLocal) ---
__global__ __launch_bounds__(256) void k_part(const int* __restrict__ et, const int* __restrict__ ei,
                       const int* __restrict__ histG, unsigned* __restrict__ payload,
                       int E, int NCHUNK, int NBUCK){
  __shared__ int cur[256];
  const int c = blockIdx.x, t = threadIdx.x;
  if (t < NBUCK) cur[t] = histG[t*NCHUNK + c];
  __syncthreads();
  const int* dstp = ei + E;
  const int base = c*CHUNK;
  #pragma unroll 4
  for (int it=0; it<CHUNK/256; ++it){
    int e = base + it*256 + t;
    if (e < E){
      int d = dstp[e];
      int s = ei[e];
      int r = et[e];
      int b = d >> BUCK_SHIFT;
      int pos = atomicAdd(&cur[b], 1);
      payload[pos] = (unsigned)((d & (DPB-1)) | (r<<8) | (s<<10));
    }
  }
}

// --- pass 4: per-bucket exact CSR (offs + ssrc), all within one block's L2 window ---
__global__ __launch_bounds__(256) void k_csr(const unsigned* __restrict__ payload,
                     const int* __restrict__ histG, int* __restrict__ offs,
                     int* __restrict__ ssrc, int E, int NCHUNK, int NBUCK){
  __shared__ int cnt[KPB];
  __shared__ int ps[256];
  const int b = blockIdx.x, t = threadIdx.x;
  const int bs = histG[b*NCHUNK];
  const int be = (b+1 < NBUCK) ? histG[(b+1)*NCHUNK] : E;

  for (int k=t; k<KPB; k+=256) cnt[k] = 0;
  __syncthreads();
  for (int i=bs+t; i<be; i+=256){
    unsigned p = payload[i];
    int lkey = (int)(p & 255u)*3 + (int)((p>>8)&3u);
    atomicAdd(&cnt[lkey], 1);
  }
  __syncthreads();
  // exclusive scan over 768 local keys; thread t owns [3t, 3t+3)
  int s0 = cnt[3*t], s1 = cnt[3*t+1], s2 = cnt[3*t+2];
  int sum = s0+s1+s2;
  ps[t] = sum; __syncthreads();
  int x = sum;
  for (int off=1; off<256; off<<=1){
    int y = (t>=off)?ps[t-off]:0; __syncthreads();
    x += y; ps[t] = x; __syncthreads();
  }
  int ex = x - sum;
  offs[b*KPB + 3*t]   = bs + ex;
  offs[b*KPB + 3*t+1] = bs + ex + s0;
  offs[b*KPB + 3*t+2] = bs + ex + s0 + s1;
  // reuse cnt as local cursor
  cnt[3*t] = ex; cnt[3*t+1] = ex + s0; cnt[3*t+2] = ex + s0 + s1;
  __syncthreads();
  for (int i=bs+t; i<be; i+=256){
    unsigned p = payload[i];
    int lkey = (int)(p & 255u)*3 + (int)((p>>8)&3u);
    int pos = bs + atomicAdd(&cnt[lkey], 1);
    ssrc[pos] = (int)(p >> 10);
  }
}

// --- per-dst: single fused pass (no max shift): num += e*h, den += e, scale at end ---
// CSR key layout: key = dst*3 + r
__global__ __launch_bounds__(256) void k_segment(
    const int* __restrict__ offs, const int* __restrict__ ssrc,
    const unsigned* __restrict__ hq,
    const float* __restrict__ as_, const float* __restrict__ ad_,
    const float* __restrict__ bias, const float* __restrict__ smw,
    float* __restrict__ out, int N){
  const int wave = threadIdx.x >> 6;
  const int lane = threadIdx.x & 63;
  const int dst  = blockIdx.x*4 + wave;
  if (dst >= N) return;
  const int g  = lane >> 3;   // edge group 0..7
  const int l8 = lane & 7;    // channel slot in group
  const int h0 = (l8 >> 2) & 1;

  float sw[NREL];
  sw[0] = smw[0]; sw[1] = smw[1]; sw[2] = smw[2];

  float accT0[8], accT1[8];
  #pragma unroll
  for (int q=0; q<8; q++){ accT0[q]=0.f; accT1[q]=0.f; }

  #pragma unroll
  for (int r=0; r<NREL; r++){
    const size_t segA = (size_t)r*N + dst;       // table index (rel-major)
    const int    key  = dst*3 + r;               // CSR index (dst-major)
    int beg = __builtin_amdgcn_readfirstlane(offs[key]);
    int end = __builtin_amdgcn_readfirstlane(offs[key+1]);

    float4 a = ((const float4*)as_)[segA];
    float4 b = ((const float4*)ad_)[segA];
    float sv0 = leaky((h0 ? a.y : a.x) + (h0 ? b.y : b.x));
    float sv1 = leaky((h0 ? a.w : a.z) + (h0 ? b.w : b.z));
    float es0 = __expf(sv0), es1 = __expf(sv1);
    float adv0 = h0 ? b.y : b.x;
    float adv1 = h0 ? b.w : b.z;

    float den0 = 0.f, den1 = 0.f;
    float acc0[8], acc1[8];
    #pragma unroll
    for (int q=0; q<8; q++){ acc0[q]=0.f; acc1[q]=0.f; }

    const unsigned* hb = hq + (size_t)r*N*64;
    const float4* atab = (const float4*)as_ + (size_t)r*N;
    for (int i0=beg; i0<end; i0+=8){
      int i = i0 + g;
      if (i < end){
        int s = ssrc[i];
        float4 a4 = atab[s];
        float s0 = (h0 ? a4.y : a4.x) + adv0;
        float s1 = (h0 ? a4.w : a4.z) + adv1;
        float e0 = __expf(leaky(s0));
        float e1 = __expf(leaky(s1));
        den0 += e0; den1 += e1;
        const uint4* hp = (const uint4*)(hb + (size_t)s*64 + l8*4);
        uint4 u0 = hp[0];
        uint4 u1 = hp[8];
        const unsigned* p0 = (const unsigned*)&u0;
        const unsigned* p1 = (const unsigned*)&u1;
        #pragma unroll
        for (int q=0; q<4; q++){
          acc0[2*q]   = fmaf(e0, __uint_as_float(p0[q]<<16),           acc0[2*q]);
          acc0[2*q+1] = fmaf(e0, __uint_as_float(p0[q] & 0xFFFF0000u), acc0[2*q+1]);
          acc1[2*q]   = fmaf(e1, __uint_as_float(p1[q]<<16),           acc1[2*q]);
          acc1[2*q+1] = fmaf(e1, __uint_as_float(p1[q] & 0xFFFF0000u), acc1[2*q+1]);
        }
      }
    }
    if (g == 0){
      const uint4* hp = (const uint4*)(hb + (size_t)dst*64 + l8*4);
      uint4 u0 = hp[0];
      uint4 u1 = hp[8];
      const unsigned* p0 = (const unsigned*)&u0;
      const unsigned* p1 = (const unsigned*)&u1;
      #pragma unroll
      for (int q=0; q<4; q++){
        acc0[2*q]   = fmaf(es0, __uint_as_float(p0[q]<<16),           acc0[2*q]);
        acc0[2*q+1] = fmaf(es0, __uint_as_float(p0[q] & 0xFFFF0000u), acc0[2*q+1]);
        acc1[2*q]   = fmaf(es1, __uint_as_float(p1[q]<<16),           acc1[2*q]);
        acc1[2*q+1] = fmaf(es1, __uint_as_float(p1[q] & 0xFFFF0000u), acc1[2*q+1]);
      }
    }
    #pragma unroll
    for (int o=8; o<=32; o<<=1){
      den0 += __shfl_xor(den0, o);
      den1 += __shfl_xor(den1, o);
    }
    den0 += es0; den1 += es1;
    float iv0 = sw[r] / den0;
    float iv1 = sw[r] / den1;
    #pragma unroll
    for (int q=0; q<8; q++){
      accT0[q] = fmaf(iv0, acc0[q], accT0[q]);
      accT1[q] = fmaf(iv1, acc1[q], accT1[q]);
    }
  }

  #pragma unroll
  for (int o=8; o<=32; o<<=1){
    #pragma unroll
    for (int q=0; q<8; q++){
      accT0[q] += __shfl_xor(accT0[q], o);
      accT1[q] += __shfl_xor(accT1[q], o);
    }
  }

  if (g == 0){
    float b0[8], b1[8];
    #pragma unroll
    for (int q=0; q<8; q++){ b0[q]=0.f; b1[q]=0.f; }
    #pragma unroll
    for (int r=0; r<NREL; r++){
      const float* bp = bias + (size_t)r*OUT_DIM;
      float4 x0 = *(const float4*)(bp + 8*l8);
      float4 x1 = *(const float4*)(bp + 8*l8 + 4);
      float4 y0 = *(const float4*)(bp + 64 + 8*l8);
      float4 y1 = *(const float4*)(bp + 64 + 8*l8 + 4);
      float w = sw[r];
      b0[0]=fmaf(w,x0.x,b0[0]); b0[1]=fmaf(w,x0.y,b0[1]); b0[2]=fmaf(w,x0.z,b0[2]); b0[3]=fmaf(w,x0.w,b0[3]);
      b0[4]=fmaf(w,x1.x,b0[4]); b0[5]=fmaf(w,x1.y,b0[5]); b0[6]=fmaf(w,x1.z,b0[6]); b0[7]=fmaf(w,x1.w,b0[7]);
      b1[0]=fmaf(w,y0.x,b1[0]); b1[1]=fmaf(w,y0.y,b1[1]); b1[2]=fmaf(w,y0.z,b1[2]); b1[3]=fmaf(w,y0.w,b1[3]);
      b1[4]=fmaf(w,y1.x,b1[4]); b1[5]=fmaf(w,y1.y,b1[5]); b1[6]=fmaf(w,y1.z,b1[6]); b1[7]=fmaf(w,y1.w,b1[7]);
    }
    float* orow = out + (size_t)dst*128;
    float4 o0 = {accT0[0]+b0[0], accT0[1]+b0[1], accT0[2]+b0[2], accT0[3]+b0[3]};
    float4 o1 = {accT0[4]+b0[4], accT0[5]+b0[5], accT0[6]+b0[6], accT0[7]+b0[7]};
    float4 o2 = {accT1[0]+b1[0], accT1[1]+b1[1], accT1[2]+b1[2], accT1[3]+b1[3]};
    float4 o3 = {accT1[4]+b1[4], accT1[5]+b1[5], accT1[6]+b1[6], accT1[7]+b1[7]};
    *(float4*)(orow + 8*l8)          = o0;
    *(float4*)(orow + 8*l8 + 4)      = o1;
    *(float4*)(orow + 64 + 8*l8)     = o2;
    *(float4*)(orow + 64 + 8*l8 + 4) = o3;
  }
}

extern "C" void kernel_launch(void* const* d_in, const int* in_sizes, int n_in,
                              void* d_out, int out_size, void* d_ws, size_t ws_size,
                              hipStream_t stream) {
  const float* x     = (const float*)d_in[0];
  const float* W     = (const float*)d_in[1];
  const float* att_s = (const float*)d_in[2];
  const float* att_d = (const float*)d_in[3];
  const float* bias  = (const float*)d_in[4];
  const float* rw    = (const float*)d_in[5];
  const int*   ei    = (const int*)d_in[6];
  const int*   et    = (const int*)d_in[7];
  float* out = (float*)d_out;

  const int N = in_sizes[0] / IN_DIM;
  const int E = in_sizes[7];
  const int M = NREL * N;
  const int NCHUNK = (E + CHUNK - 1) / CHUNK;
  const int NBUCK  = (N + DPB - 1) / DPB;

  char* ws = (char*)d_ws;
  size_t off = 0;
  auto alloc = [&](size_t bytes) -> void* {
    void* p = ws + off; off += (bytes + 255) & ~(size_t)255; return p;
  };
  unsigned* hq      = (unsigned*)alloc((size_t)M * 64 * 4);
  float*    as_     = (float*)   alloc((size_t)M * 4 * 4);
  float*    ad_     = (float*)   alloc((size_t)M * 4 * 4);
  int*      offs    = (int*)     alloc(((size_t)NBUCK*KPB + 1) * 4);
  int*      histG   = (int*)     alloc((size_t)NBUCK * NCHUNK * 4);
  unsigned* payload = (unsigned*)alloc((size_t)E * 4);
  int*      ssrc    = (int*)     alloc((size_t)E * 4);
  float*    smw     = (float*)   alloc(256);
  u16*      WTall   = (u16*)     alloc((size_t)NREL * 144 * 128 * 2);

  k_prep<<<1, 64, 0, stream>>>(rw, smw);
  k_wprep<<<NREL, 256, 0, stream>>>(W, att_s, att_d, WTall);
  dim3 g1((N + 127) / 128, NREL);
  k_gemm<<<g1, 256, 0, stream>>>(x, WTall, hq, as_, ad_, N);
  k_hist<<<NCHUNK, 256, 0, stream>>>(ei, histG, E, NCHUNK, NBUCK);
  k_scanH<<<1, 256, 0, stream>>>(histG, NBUCK * NCHUNK);
  k_part<<<NCHUNK, 256, 0, stream>>>(et, ei, histG, payload, E, NCHUNK, NBUCK);
  k_csr<<<NBUCK, 256, 0, stream>>>(payload, histG, offs, ssrc, E, NCHUNK, NBUCK);
  k_segment<<<(N + 3) / 4, 256, 0, stream>>>(offs, ssrc, hq, as_, ad_, bias, smw, out, N);
}